// Round 6
// baseline (49.760 us; speedup 1.0000x reference)
//
#include <hip/hip_runtime.h>

typedef float v2 __attribute__((ext_vector_type(2)));

#define H     128
#define W     128
#define HO    126
#define WO    126
#define NPIX  (HO * WO)      // 15876
#define YPB   4              // y-pairs per block (last block: 3)
#define TH    17             // padded LDS column height (odd -> spread banks)
#define BPP   16             // blocks per plane (15*4 + 3 = 63 y-pairs)

__global__ __launch_bounds__(1024) void zero_out(float* __restrict__ out) {
    out[threadIdx.x] = 0.f;
}

// One thread = one 2px-wide x 2row quad, all math in float2 (v_pk_*_f32).
// LDS tile is column-major so y-pairs are adjacent dwords (1 load, 0 movs).
__global__ __launch_bounds__(256, 6) void bp_kernel(const float* __restrict__ x,
                                                    float* __restrict__ out) {
    __shared__ float tileT[W * TH];   // tileT[col*TH + row], 8704 B
    __shared__ float wsum[4];

    const int bid   = blockIdx.x;
    const int plane = bid >> 4;
    const int cb    = bid & 15;
    const int np    = (cb == 15) ? 3 : YPB;   // y-pairs in this block
    const int r0    = cb * (2 * YPB);         // first staged input row
    const int nr    = 2 * np + 2;             // staged rows (10 or 8)
    const int tid   = threadIdx.x;

    // ---- stage: global row-major (coalesced float4) -> LDS column-major ----
    const float4* src4 = (const float4*)(x + (size_t)plane * (H * W) + (size_t)r0 * W);
    for (int i = tid; i < nr * 32; i += 256) {
        const int row = i >> 5, j = i & 31;
        const float4 v = src4[row * 32 + j];
        float* dst = &tileT[(4 * j) * TH + row];
        dst[0]      = v.x;
        dst[TH]     = v.y;
        dst[2 * TH] = v.z;
        dst[3 * TH] = v.w;
    }
    __syncthreads();

    v2 acc2 = {0.f, 0.f};

    const int gx = tid % 63;      // x-group: cols 2gx..2gx+3, out px 2gx,2gx+1
    const int p  = tid / 63;      // local y-pair (out rows 2p,2p+1 of chunk)

    if (p < np) {
        const float* base = &tileT[(2 * gx) * TH + 2 * p];

        // P[i][c] = {tile[2p+i][2gx+c], tile[2p+i+1][2gx+c]} -- adjacent dwords
        v2 P[3][4];
#pragma unroll
        for (int c = 0; c < 4; ++c) {
            const float* q = base + c * TH;
#pragma unroll
            for (int i = 0; i < 3; ++i)
                P[i][c] = (v2){q[i], q[i + 1]};
        }

        v2 cs[4];
#pragma unroll
        for (int c = 0; c < 4; ++c)
            cs[c] = P[0][c] + P[1][c] + P[2][c];

        const v2 Z    = {0.f, 0.f};
        const v2 C19  = {1.f / 9.f, 1.f / 9.f};
        const v2 CNS  = {-1.f / 2295.f, -1.f / 2295.f};

#pragma unroll
        for (int k = 0; k < 2; ++k) {
            const v2 ctr = P[1][k + 1];
            const v2 sum = cs[k] + cs[k + 1] + cs[k + 2];

            // sum of squares over 9 taps (1 pk_mul + 8 pk_fma)
            v2 ss = P[0][k] * P[0][k];
            ss = __builtin_elementwise_fma(P[1][k],     P[1][k],     ss);
            ss = __builtin_elementwise_fma(P[2][k],     P[2][k],     ss);
            ss = __builtin_elementwise_fma(P[0][k + 1], P[0][k + 1], ss);
            ss = __builtin_elementwise_fma(P[1][k + 1], P[1][k + 1], ss);
            ss = __builtin_elementwise_fma(P[2][k + 1], P[2][k + 1], ss);
            ss = __builtin_elementwise_fma(P[0][k + 2], P[0][k + 2], ss);
            ss = __builtin_elementwise_fma(P[1][k + 2], P[1][k + 2], ss);
            ss = __builtin_elementwise_fma(P[2][k + 2], P[2][k + 2], ss);

            // window max over 9 taps (8 pk_max)
            v2 wmax = __builtin_elementwise_max(
                __builtin_elementwise_max(
                    __builtin_elementwise_max(P[0][k],     P[1][k]),
                    __builtin_elementwise_max(P[2][k],     P[0][k + 1])),
                __builtin_elementwise_max(
                    __builtin_elementwise_max(P[1][k + 1], P[2][k + 1]),
                    __builtin_elementwise_max(
                        __builtin_elementwise_max(P[0][k + 2], P[1][k + 2]),
                        P[2][k + 2])));

            // diffs (center excluded) -- 8 pk_sub
            const v2 d0 = P[0][k]     - ctr;
            const v2 d1 = P[0][k + 1] - ctr;
            const v2 d2 = P[0][k + 2] - ctr;
            const v2 d3 = P[1][k]     - ctr;
            const v2 d4 = P[1][k + 2] - ctr;
            const v2 d5 = P[2][k]     - ctr;
            const v2 d6 = P[2][k + 1] - ctr;
            const v2 d7 = P[2][k + 2] - ctr;

            // sad = sum |d| : |d| = max(d,-d) (pk_max w/ neg mod) + pk_add tree
            const v2 sad =
                ((__builtin_elementwise_max(d0, -d0) + __builtin_elementwise_max(d1, -d1)) +
                 (__builtin_elementwise_max(d2, -d2) + __builtin_elementwise_max(d3, -d3))) +
                ((__builtin_elementwise_max(d4, -d4) + __builtin_elementwise_max(d5, -d5)) +
                 (__builtin_elementwise_max(d6, -d6) + __builtin_elementwise_max(d7, -d7)));

            const v2 thr = sad * C19;

            // tap counts (scalar compares; no pk cmp exists)
            int bx = (sad.x <= 0.f) ? 1 : 0;   // center tap: 0 >= thr
            int by = (sad.y <= 0.f) ? 1 : 0;
            bx += d0.x >= thr.x;  by += d0.y >= thr.y;
            bx += d1.x >= thr.x;  by += d1.y >= thr.y;
            bx += d2.x >= thr.x;  by += d2.y >= thr.y;
            bx += d3.x >= thr.x;  by += d3.y >= thr.y;
            bx += d4.x >= thr.x;  by += d4.y >= thr.y;
            bx += d5.x >= thr.x;  by += d5.y >= thr.y;
            bx += d6.x >= thr.x;  by += d6.y >= thr.y;
            bx += d7.x >= thr.x;  by += d7.y >= thr.y;
            const v2 bv = {(float)bx, (float)by};

            const v2 var81 = __builtin_elementwise_fma(sum, -sum, ss * 9.f);
            const v2 var81c = __builtin_elementwise_max(var81, Z);
            const v2 sd9 = {__builtin_amdgcn_sqrtf(var81c.x),
                            __builtin_amdgcn_sqrtf(var81c.y)};

            const v2 nf = __builtin_elementwise_fma(sum, CNS, bv * (1.f / 255.f));
            const v2 t1 = __builtin_elementwise_fma(sd9, C19, -wmax);
            acc2 += __builtin_elementwise_fma(nf, t1, wmax);
        }
    }

    // ---- block reduction + atomic combine across the 16 chunk-blocks ----
    float acc = acc2.x + acc2.y;
#pragma unroll
    for (int off = 32; off > 0; off >>= 1)
        acc += __shfl_down(acc, off, 64);
    if ((tid & 63) == 0) wsum[tid >> 6] = acc;
    __syncthreads();
    if (tid == 0)
        atomicAdd(out + plane,
                  (wsum[0] + wsum[1] + wsum[2] + wsum[3]) * (1.f / NPIX));
}

extern "C" void kernel_launch(void* const* d_in, const int* in_sizes, int n_in,
                              void* d_out, int out_size, void* d_ws, size_t ws_size,
                              hipStream_t stream) {
    const float* x = (const float*)d_in[0];
    float* out = (float*)d_out;
    zero_out<<<dim3(1), dim3(1024), 0, stream>>>(out);
    bp_kernel<<<dim3(16 * 64 * BPP), dim3(256), 0, stream>>>(x, out);
}

// Round 8
// 41.224 us; speedup vs baseline: 1.2071x; 1.2071x over previous
//
#include <hip/hip_runtime.h>

#define H     128
#define W     128
#define HO    126
#define WO    126
#define NPIX  (HO * WO)          // 15876
#define CHUNKS 8
#define CROWS 16                 // output rows per chunk (constant trip count)
#define TROWS 18                 // staged input rows (constant)
#define TSZ   (TROWS * W + 8)

__global__ __launch_bounds__(1024) void zero_out(float* __restrict__ out) {
    out[threadIdx.x] = 0.f;
}

// One block per (plane, 16-row chunk). Chunk 7 stages from row 110 (constant
// shape) but output rows 110-111 belong to chunk 6 -> mask y<2 there.
__global__ __launch_bounds__(256) void bp_kernel(const float* __restrict__ x,
                                                 float* __restrict__ out) {
    __shared__ float tile[TSZ];
    __shared__ float wsum[4];

    const int bid   = blockIdx.x;
    const int plane = bid >> 3;
    const int c     = bid & 7;
    const bool last = (c == 7);
    const int r0    = last ? (HO - CROWS) : c * CROWS;   // 110 or 16c
    const int tid   = threadIdx.x;

    // ---- stage 18 rows (linear, coalesced) ----
    const float4* src4 = (const float4*)(x + (size_t)plane * (H * W) + (size_t)r0 * W);
    float4* t4 = (float4*)tile;
    for (int i = tid; i < TROWS * 32; i += 256)
        t4[i] = src4[i];
    __syncthreads();

    float acc = 0.f;

#pragma unroll
    for (int it = 0; it < 2; ++it) {
        const int g  = tid + it * 256;       // 512 groups: 16 rows x 32
        const int y  = g >> 5;
        const int xq = g & 31;
        const int x0 = xq << 2;

        float r[3][6];
#pragma unroll
        for (int dr = 0; dr < 3; ++dr) {
            const float* rowp = &tile[(y + dr) * W + x0];
            const float4 a = *(const float4*)rowp;       // cols x0..x0+3
            const float2 b = *(const float2*)(rowp + 4); // cols x0+4,x0+5 (garbage at xq=31 -> masked px only)
            r[dr][0] = a.x; r[dr][1] = a.y; r[dr][2] = a.z; r[dr][3] = a.w;
            r[dr][4] = b.x; r[dr][5] = b.y;
        }

        float cs[6], cq[6], cm[6];
#pragma unroll
        for (int cc = 0; cc < 6; ++cc) {
            cs[cc] = r[0][cc] + r[1][cc] + r[2][cc];
            cq[cc] = fmaf(r[0][cc], r[0][cc], fmaf(r[1][cc], r[1][cc], r[2][cc] * r[2][cc]));
            cm[cc] = fmaxf(r[0][cc], fmaxf(r[1][cc], r[2][cc]));   // -> v_max3
        }

        float bnv[4];
#pragma unroll
        for (int k = 0; k < 4; ++k) {
            const float ctr  = r[1][k + 1];
            const float sum  = cs[k] + cs[k + 1] + cs[k + 2];
            const float ss   = cq[k] + cq[k + 1] + cq[k + 2];
            const float wmax = fmaxf(cm[k], fmaxf(cm[k + 1], cm[k + 2]));

            float d[8];
            d[0] = r[0][k]     - ctr;  d[1] = r[0][k + 1] - ctr;
            d[2] = r[0][k + 2] - ctr;  d[3] = r[1][k]     - ctr;
            d[4] = r[1][k + 2] - ctr;  d[5] = r[2][k]     - ctr;
            d[6] = r[2][k + 1] - ctr;  d[7] = r[2][k + 2] - ctr;

            const float sad = ((fabsf(d[0]) + fabsf(d[1])) + (fabsf(d[2]) + fabsf(d[3])))
                            + ((fabsf(d[4]) + fabsf(d[5])) + (fabsf(d[6]) + fabsf(d[7])));
            const float thr = sad * (1.f / 9.f);

            // two independent carry trees (break the 9-deep addc chain)
            int b0 = (sad <= 0.f) ? 1 : 0;    // center tap: 0 >= thr
            b0 += d[0] >= thr;
            b0 += d[1] >= thr;
            b0 += d[2] >= thr;
            b0 += d[3] >= thr;
            int b1 = d[4] >= thr;
            b1 += d[5] >= thr;
            b1 += d[6] >= thr;
            b1 += d[7] >= thr;
            const float bv = (float)(b0 + b1);

            const float var9 = fmaf(sum, -sum, 9.f * ss);                // 81*var
            const float sd9  = __builtin_amdgcn_sqrtf(fmaxf(var9, 0.f)); // 9*std
            const float nf   = fmaf(sum, -1.f / 2295.f, bv * (1.f / 255.f));
            bnv[k] = fmaf(nf, fmaf(sd9, 1.f / 9.f, -wmax), wmax);
        }

        // k=0,1 always in-bounds; k=2,3 only when xq<31 (WO=126=4*31+2)
        float gsum = bnv[0] + bnv[1];
        gsum += (xq < 31) ? (bnv[2] + bnv[3]) : 0.f;

        // chunk 7 rows 110-111 (y<2) are owned by chunk 6 -- drop them.
        // Only reachable in it==0 (it==1 has y>=8), so the select exists once.
        if (it == 0)
            gsum = (last && y < 2) ? 0.f : gsum;
        acc += gsum;
    }

    // ---- block reduction + atomic combine ----
#pragma unroll
    for (int off = 32; off > 0; off >>= 1)
        acc += __shfl_down(acc, off, 64);
    if ((tid & 63) == 0) wsum[tid >> 6] = acc;
    __syncthreads();
    if (tid == 0)
        atomicAdd(out + plane,
                  (wsum[0] + wsum[1] + wsum[2] + wsum[3]) * (1.f / NPIX));
}

extern "C" void kernel_launch(void* const* d_in, const int* in_sizes, int n_in,
                              void* d_out, int out_size, void* d_ws, size_t ws_size,
                              hipStream_t stream) {
    const float* x = (const float*)d_in[0];
    float* out = (float*)d_out;
    zero_out<<<dim3(1), dim3(1024), 0, stream>>>(out);
    bp_kernel<<<dim3(16 * 64 * CHUNKS), dim3(256), 0, stream>>>(x, out);
}